// Round 3
// baseline (373.624 us; speedup 1.0000x reference)
//
#include <hip/hip_runtime.h>

#define N_TOK 4096
#define DIM   1024
#define NE    8
#define CAP   1280
#define EC    (NE * CAP)           // 10240 floats per token per tensor
#define NEC   ((size_t)N_TOK * EC) // 41943040

// Output = 8 floats (used) + 2 * NEC floats (cb_weight, sec_mask) = 83,886,088
// floats = 20,971,522 float4. Fill with 2048 blocks x 256 threads x 40 float4
// contiguous chunks (10240 f4 / block), 2 f4 tail handled by block 0.
#define NB_FILL   2048
#define F4_TOTAL  ((2 * NEC + 8) / 4)      // 20971522
#define F4_BLOCK  (40 * 256)               // 10240
#define F4_MAIN   ((size_t)NB_FILL * F4_BLOCK)

typedef float nt_float4 __attribute__((ext_vector_type(4)));

// ---------------- Stage 1: fused zero-fill + logits/softmax/top2 -------------
// All 2048 blocks zero-fill a contiguous 2.6 MB chunk of out with plain
// coalesced float4 stores (rocclr-fill style). Blocks < 1024 first compute
// logits for 4 tokens (one wave each); the 16.8 MB x-read hides under the
// 335.5 MB store stream.
__global__ __launch_bounds__(256) void k_fill_logits(const float* __restrict__ x,
                                                     const float* __restrict__ wg,
                                                     int* __restrict__ top_idx,   // [2*N] k-major
                                                     float* __restrict__ top_p,   // [2*N] k-major
                                                     float* __restrict__ out) {
    __shared__ float swg[NE * DIM];
    const int bid = blockIdx.x;
    const int tid = threadIdx.x;

    if (bid < N_TOK / 4) {
        const float4* wg4 = (const float4*)wg;
        float4* swg4 = (float4*)swg;
#pragma unroll
        for (int i = 0; i < 8; ++i) {
            int t = i * 256 + tid;
            swg4[t] = wg4[t];
        }
        __syncthreads();

        const int wave = tid >> 6;
        const int lane = tid & 63;
        const int token = bid * 4 + wave;

        const float4* x4 = (const float4*)(x + (size_t)token * DIM);
        float acc[NE];
#pragma unroll
        for (int e = 0; e < NE; ++e) acc[e] = 0.f;

#pragma unroll
        for (int c = 0; c < 4; ++c) {
            float4 xv = x4[c * 64 + lane];
#pragma unroll
            for (int e = 0; e < NE; ++e) {
                float4 wv = swg4[e * 256 + c * 64 + lane];
                acc[e] += xv.x * wv.x + xv.y * wv.y + xv.z * wv.z + xv.w * wv.w;
            }
        }
#pragma unroll
        for (int e = 0; e < NE; ++e) {
            float v = acc[e];
#pragma unroll
            for (int off = 32; off > 0; off >>= 1)
                v += __shfl_xor(v, off, 64);
            acc[e] = v;
        }

        if (lane == 0) {
            float m = acc[0];
#pragma unroll
            for (int e = 1; e < NE; ++e) m = fmaxf(m, acc[e]);
            float pe[NE];
            float s = 0.f;
#pragma unroll
            for (int e = 0; e < NE; ++e) { pe[e] = expf(acc[e] - m); s += pe[e]; }
            float inv = 1.f / s;

            int i1 = 0; float v1 = acc[0];
#pragma unroll
            for (int e = 1; e < NE; ++e) if (acc[e] > v1) { v1 = acc[e]; i1 = e; }
            int i2 = (i1 == 0) ? 1 : 0; float v2 = acc[i2];
#pragma unroll
            for (int e = 0; e < NE; ++e)
                if (e != i1 && acc[e] > v2) { v2 = acc[e]; i2 = e; }

            top_idx[token]         = i1;
            top_idx[N_TOK + token] = i2;
            top_p[token]           = pe[i1] * inv;
            top_p[N_TOK + token]   = pe[i2] * inv;
        }
    }

    // ---- bulk zero-fill: contiguous per-block chunk, lane-coalesced ----
    nt_float4 z = (nt_float4)0.f;
    nt_float4* o4 = (nt_float4*)out;
    const size_t base = (size_t)bid * F4_BLOCK + tid;
#pragma unroll
    for (int i = 0; i < 40; ++i)
        o4[base + i * 256] = z;
    if (bid == 0 && tid < (int)(F4_TOTAL - F4_MAIN))
        o4[F4_MAIN + tid] = z;
}

// ---------------- Stage 2: rank (order-exact cumsum) + sparse scatter --------
// Single block. Rank must reproduce the reference's j = k*N+n cumsum order, so
// it stays a sequential scan (histogram + wave scan + cross-wave combine).
// dest kept in LDS; after a syncthreads the same block scatters the <=16384
// nonzero elements + 8 used-capacity values into the pre-zeroed output.
// Top-1 and top-2 of a token are distinct experts -> no write collisions.
__global__ __launch_bounds__(256) void k_rank_scatter(const int* __restrict__ top_idx,
                                                      const float* __restrict__ top_p,
                                                      float* __restrict__ out) {
    __shared__ int se[2 * N_TOK];     // 32 KB
    __shared__ int sdest[2 * N_TOK];  // 32 KB
    __shared__ int wsum[4][NE];
    const int t = threadIdx.x;
    const int lane = t & 63;
    const int wave = t >> 6;

    const int4* ti4 = (const int4*)top_idx;
    int4* se4 = (int4*)se;
#pragma unroll
    for (int i = 0; i < 8; ++i)
        se4[i * 256 + t] = ti4[i * 256 + t];
    __syncthreads();

    // pass 1: branchless per-thread histogram over 32 items
    int cnt[NE];
#pragma unroll
    for (int e = 0; e < NE; ++e) cnt[e] = 0;
    const int base = t * 32;
#pragma unroll
    for (int jj = 0; jj < 32; ++jj) {
        int v = se[base + jj];
#pragma unroll
        for (int e = 0; e < NE; ++e) cnt[e] += (v == e) ? 1 : 0;
    }

    // wave-inclusive scan per expert, then cross-wave combine via LDS
    int incl[NE];
#pragma unroll
    for (int e = 0; e < NE; ++e) {
        int s = cnt[e];
#pragma unroll
        for (int off = 1; off < 64; off <<= 1) {
            int u = __shfl_up(s, off, 64);
            if (lane >= off) s += u;
        }
        incl[e] = s;
        if (lane == 63) wsum[wave][e] = s;
    }
    __syncthreads();

    int excl[NE];
#pragma unroll
    for (int e = 0; e < NE; ++e) {
        int off = 0;
#pragma unroll
        for (int w = 0; w < 4; ++w)
            off += (w < wave) ? wsum[w][e] : 0;
        excl[e] = off + incl[e] - cnt[e];
    }
    if (t < NE) {
        int total = wsum[0][t] + wsum[1][t] + wsum[2][t] + wsum[3][t];
        out[t] = (float)min(total, CAP);   // used_capacity (out[0..7] pre-zeroed)
    }

    // pass 2: branchless rank assignment -> dest element index (in LDS)
    int run[NE];
#pragma unroll
    for (int e = 0; e < NE; ++e) run[e] = excl[e];
#pragma unroll
    for (int jj = 0; jj < 32; ++jj) {
        int j = base + jj;
        int v = se[j];
        int r = run[0];
#pragma unroll
        for (int e = 1; e < NE; ++e) r = (v == e) ? run[e] : r;
#pragma unroll
        for (int e = 0; e < NE; ++e) run[e] += (v == e) ? 1 : 0;
        sdest[j] = (r < CAP) ? (v * CAP + r) : -1;
    }
    __syncthreads();

    // scatter: <=2 nonzero elements per token into cb_weight + sec_mask
#pragma unroll
    for (int jj = 0; jj < 32; ++jj) {
        int j = jj * 256 + t;
        int d = sdest[j];
        if (d >= 0) {
            int n = j & (N_TOK - 1);
            float w = top_p[j];
            out[8 + (size_t)n * EC + d]       = w;
            out[8 + NEC + (size_t)n * EC + d] = (w != 0.f) ? 1.f : 0.f;
        }
    }
}

extern "C" void kernel_launch(void* const* d_in, const int* in_sizes, int n_in,
                              void* d_out, int out_size, void* d_ws, size_t ws_size,
                              hipStream_t stream) {
    const float* x  = (const float*)d_in[0];
    const float* wg = (const float*)d_in[1];
    float* out = (float*)d_out;
    char* ws = (char*)d_ws;

    int*   top_idx = (int*)(ws);             // 8192 ints   (32 KB)
    float* top_p   = (float*)(ws + 32768);   // 8192 floats (32 KB)

    k_fill_logits<<<NB_FILL, 256, 0, stream>>>(x, wg, top_idx, top_p, out);
    k_rank_scatter<<<1, 256, 0, stream>>>(top_idx, top_p, out);
}

// Round 4
// 371.764 us; speedup vs baseline: 1.0050x; 1.0050x over previous
//
#include <hip/hip_runtime.h>

#define N_TOK 4096
#define DIM   1024
#define NE    8
#define CAP   1280
#define EC    (NE * CAP)           // 10240 floats per token per tensor
#define NEC   ((size_t)N_TOK * EC) // 41943040

// ---------------- Stage 1: logits -> softmax -> top2 ----------------
// One wave per token (4 waves / block). w_g (32 KB) staged in LDS.
__global__ __launch_bounds__(256) void k_logits(const float* __restrict__ x,
                                                const float* __restrict__ wg,
                                                int* __restrict__ top_idx,   // [2*N] k-major
                                                float* __restrict__ top_p) { // [2*N] k-major
    __shared__ float swg[NE * DIM];
    const float4* wg4 = (const float4*)wg;
    float4* swg4 = (float4*)swg;
#pragma unroll
    for (int i = 0; i < 8; ++i) {
        int t = i * 256 + threadIdx.x;
        swg4[t] = wg4[t];
    }
    __syncthreads();

    const int wave = threadIdx.x >> 6;
    const int lane = threadIdx.x & 63;
    const int token = blockIdx.x * 4 + wave;

    const float4* x4 = (const float4*)(x + (size_t)token * DIM);
    float acc[NE];
#pragma unroll
    for (int e = 0; e < NE; ++e) acc[e] = 0.f;

#pragma unroll
    for (int c = 0; c < 4; ++c) {
        float4 xv = x4[c * 64 + lane];
#pragma unroll
        for (int e = 0; e < NE; ++e) {
            float4 wv = swg4[e * 256 + c * 64 + lane];
            acc[e] += xv.x * wv.x + xv.y * wv.y + xv.z * wv.z + xv.w * wv.w;
        }
    }
#pragma unroll
    for (int e = 0; e < NE; ++e) {
        float v = acc[e];
#pragma unroll
        for (int off = 32; off > 0; off >>= 1)
            v += __shfl_xor(v, off, 64);
        acc[e] = v;
    }

    if (lane == 0) {
        float m = acc[0];
#pragma unroll
        for (int e = 1; e < NE; ++e) m = fmaxf(m, acc[e]);
        float pe[NE];
        float s = 0.f;
#pragma unroll
        for (int e = 0; e < NE; ++e) { pe[e] = expf(acc[e] - m); s += pe[e]; }
        float inv = 1.f / s;

        int i1 = 0; float v1 = acc[0];
#pragma unroll
        for (int e = 1; e < NE; ++e) if (acc[e] > v1) { v1 = acc[e]; i1 = e; }
        int i2 = (i1 == 0) ? 1 : 0; float v2 = acc[i2];
#pragma unroll
        for (int e = 0; e < NE; ++e)
            if (e != i1 && acc[e] > v2) { v2 = acc[e]; i2 = e; }

        top_idx[token]         = i1;
        top_idx[N_TOK + token] = i2;
        top_p[token]           = pe[i1] * inv;
        top_p[N_TOK + token]   = pe[i2] * inv;
    }
}

// ---------------- Stage 2: rank (order-exact cumsum) + sparse scatter --------
// Single block. Rank reproduces the reference's j = k*N+n cumsum order
// (histogram + wave scan + cross-wave combine); dest stays in LDS; the same
// block then scatters the <=16384 nonzero elements + 8 used-capacity values
// into the memset-zeroed output. Top-1 and top-2 of a token are distinct
// experts -> the two writes of a token never collide.
__global__ __launch_bounds__(256) void k_rank_scatter(const int* __restrict__ top_idx,
                                                      const float* __restrict__ top_p,
                                                      float* __restrict__ out) {
    __shared__ int se[2 * N_TOK];     // 32 KB
    __shared__ int sdest[2 * N_TOK];  // 32 KB
    __shared__ int wsum[4][NE];
    const int t = threadIdx.x;
    const int lane = t & 63;
    const int wave = t >> 6;

    const int4* ti4 = (const int4*)top_idx;
    int4* se4 = (int4*)se;
#pragma unroll
    for (int i = 0; i < 8; ++i)
        se4[i * 256 + t] = ti4[i * 256 + t];
    __syncthreads();

    // pass 1: branchless per-thread histogram over 32 items
    int cnt[NE];
#pragma unroll
    for (int e = 0; e < NE; ++e) cnt[e] = 0;
    const int base = t * 32;
#pragma unroll
    for (int jj = 0; jj < 32; ++jj) {
        int v = se[base + jj];
#pragma unroll
        for (int e = 0; e < NE; ++e) cnt[e] += (v == e) ? 1 : 0;
    }

    // wave-inclusive scan per expert, then cross-wave combine via LDS
    int incl[NE];
#pragma unroll
    for (int e = 0; e < NE; ++e) {
        int s = cnt[e];
#pragma unroll
        for (int off = 1; off < 64; off <<= 1) {
            int u = __shfl_up(s, off, 64);
            if (lane >= off) s += u;
        }
        incl[e] = s;
        if (lane == 63) wsum[wave][e] = s;
    }
    __syncthreads();

    int excl[NE];
#pragma unroll
    for (int e = 0; e < NE; ++e) {
        int off = 0;
#pragma unroll
        for (int w = 0; w < 4; ++w)
            off += (w < wave) ? wsum[w][e] : 0;
        excl[e] = off + incl[e] - cnt[e];
    }
    if (t < NE) {
        int total = wsum[0][t] + wsum[1][t] + wsum[2][t] + wsum[3][t];
        out[t] = (float)min(total, CAP);   // used_capacity (out[0..7] pre-zeroed)
    }

    // pass 2: branchless rank assignment -> dest element index (in LDS)
    int run[NE];
#pragma unroll
    for (int e = 0; e < NE; ++e) run[e] = excl[e];
#pragma unroll
    for (int jj = 0; jj < 32; ++jj) {
        int j = base + jj;
        int v = se[j];
        int r = run[0];
#pragma unroll
        for (int e = 1; e < NE; ++e) r = (v == e) ? run[e] : r;
#pragma unroll
        for (int e = 0; e < NE; ++e) run[e] += (v == e) ? 1 : 0;
        sdest[j] = (r < CAP) ? (v * CAP + r) : -1;
    }
    __syncthreads();

    // scatter: <=2 nonzero elements per token into cb_weight + sec_mask
#pragma unroll
    for (int jj = 0; jj < 32; ++jj) {
        int j = jj * 256 + t;
        int d = sdest[j];
        if (d >= 0) {
            int n = j & (N_TOK - 1);
            float w = top_p[j];
            out[8 + (size_t)n * EC + d]       = w;
            out[8 + NEC + (size_t)n * EC + d] = (w != 0.f) ? 1.f : 0.f;
        }
    }
}

extern "C" void kernel_launch(void* const* d_in, const int* in_sizes, int n_in,
                              void* d_out, int out_size, void* d_ws, size_t ws_size,
                              hipStream_t stream) {
    const float* x  = (const float*)d_in[0];
    const float* wg = (const float*)d_in[1];
    float* out = (float*)d_out;
    char* ws = (char*)d_ws;

    int*   top_idx = (int*)(ws);             // 8192 ints   (32 KB)
    float* top_p   = (float*)(ws + 32768);   // 8192 floats (32 KB)

    // Bulk-zero the logical output: 8 + 2*N*E*C floats = 335.5 MB.
    // Runs as the runtime's fillBufferAligned at ~6.1 TB/s (~53 us) —
    // measured faster than any hand-rolled fill (round-3 regression).
    hipMemsetAsync(out, 0, (size_t)(8 + 2 * NEC) * sizeof(float), stream);

    k_logits<<<N_TOK / 4, 256, 0, stream>>>(x, wg, top_idx, top_p);
    k_rank_scatter<<<1, 256, 0, stream>>>(top_idx, top_p, out);
}